// Round 5
// baseline (3114.576 us; speedup 1.0000x reference)
//
#include <hip/hip_runtime.h>

// GCN 3-layer + MLP head.
// Round-5 change: k_fused uses 1024-thread blocks (16 waves). Round-4's 94us
// fused kernel was latency/MLP-bound (1.0 TB/s @ 28% occupancy; warm replays
// at 135 GB/s took the SAME 94us) because 782 blocks x 4 waves gave only
// ~12 waves/CU. 16 waves/block restores 32 waves/CU and 4x outstanding loads.
// Phase A: 4 nodes/wave gather -> LDS tile. Phase B: vector-FMA GEMM from LDS
// (2 rows/thread for 128-col, 1 row/thread for 64-col).
// Pipeline (8 launches):
//   k_gemm1_hist: g1 = bf16(x@W1), fused with dst-histogram
//   scan1/scan2 ; scatter ; finalize  -> csr, rp, dis
//   k_fused<0>(g1,b1,W2) -> g2 ; k_fused<0>(g2,b2,W3) -> g3
//   k_fused<1>(g3,b3,Wo1,bo1,Wo2,bo2) -> out
// Math: h_i = relu(dis_i*( sum_{e:dst=i} dis_src*graw_src + dis_i*graw_i )+b)
// graw = h@W stored bf16; all accumulation fp32.

#define DHID 128
#define NBUK 256   // dst buckets
#define NBLK 196   // edge-chunk blocks (NBUK*NBLK = 50176 scan elements)

static __device__ __forceinline__ unsigned short f2bf(float f) {
  unsigned int u = __float_as_uint(f);
  u += 0x7fffu + ((u >> 16) & 1u);  // round-to-nearest-even
  return (unsigned short)(u >> 16);
}
static __device__ __forceinline__ float bf_lo(unsigned int v) {
  return __uint_as_float(v << 16);
}
static __device__ __forceinline__ float bf_hi(unsigned int v) {
  return __uint_as_float(v & 0xffff0000u);
}

// ---------------- scan ----------------

__global__ __launch_bounds__(256) void k_scan1(const int* __restrict__ in,
                                               int* __restrict__ out,
                                               int* __restrict__ blk, int Mtot) {
  __shared__ int s[256];
  int tid = threadIdx.x;
  int i = blockIdx.x * 256 + tid;
  int v = (i < Mtot) ? in[i] : 0;
  s[tid] = v;
  __syncthreads();
  for (int off = 1; off < 256; off <<= 1) {
    int t = (tid >= off) ? s[tid - off] : 0;
    __syncthreads();
    s[tid] += t;
    __syncthreads();
  }
  if (i < Mtot) out[i] = s[tid] - v;  // exclusive within block
  if (tid == 255) blk[blockIdx.x] = s[255];
}

__global__ void k_scan2(int* blk, int n) {  // n <= 256
  __shared__ int s[256];
  int tid = threadIdx.x;
  int v = (tid < n) ? blk[tid] : 0;
  s[tid] = v;
  __syncthreads();
  for (int off = 1; off < 256; off <<= 1) {
    int t = (tid >= off) ? s[tid - off] : 0;
    __syncthreads();
    s[tid] += t;
    __syncthreads();
  }
  if (tid < n) blk[tid] = s[tid] - v;  // exclusive
}

// ---------------- GEMM body: [64,128] @ [128,128] -> bf16 (hist kernel) ----

__device__ __forceinline__ void gemm128_body0(const float* __restrict__ H,
                                              const float* __restrict__ W,
                                              void* __restrict__ out, int M,
                                              int row0) {
  __shared__ float4 Hs[64 * 32];  // 32 KB
  int tid = threadIdx.x;
  const float4* H4 = (const float4*)H;
#pragma unroll
  for (int i = 0; i < 8; i++) {
    int slot = tid + i * 256;  // 0..2047
    int r = slot >> 5, c4 = slot & 31;
    int gr = row0 + r;
    Hs[slot] = (gr < M) ? H4[(size_t)gr * 32 + c4] : make_float4(0.f, 0.f, 0.f, 0.f);
  }
  __syncthreads();

  int c4 = tid & 31;
  int r0 = (tid >> 5) * 8;
  const float4* W4 = (const float4*)W;
  float4 acc[8];
#pragma unroll
  for (int r = 0; r < 8; r++) acc[r] = make_float4(0.f, 0.f, 0.f, 0.f);

  for (int k4 = 0; k4 < 32; k4++) {
    float4 w0 = W4[(k4 * 4 + 0) * 32 + c4];
    float4 w1 = W4[(k4 * 4 + 1) * 32 + c4];
    float4 w2 = W4[(k4 * 4 + 2) * 32 + c4];
    float4 w3 = W4[(k4 * 4 + 3) * 32 + c4];
#pragma unroll
    for (int r = 0; r < 8; r++) {
      float4 h = Hs[(r0 + r) * 32 + k4];
      acc[r].x = fmaf(h.w, w3.x, fmaf(h.z, w2.x, fmaf(h.y, w1.x, fmaf(h.x, w0.x, acc[r].x))));
      acc[r].y = fmaf(h.w, w3.y, fmaf(h.z, w2.y, fmaf(h.y, w1.y, fmaf(h.x, w0.y, acc[r].y))));
      acc[r].z = fmaf(h.w, w3.z, fmaf(h.z, w2.z, fmaf(h.y, w1.z, fmaf(h.x, w0.z, acc[r].z))));
      acc[r].w = fmaf(h.w, w3.w, fmaf(h.z, w2.w, fmaf(h.y, w1.w, fmaf(h.x, w0.w, acc[r].w))));
    }
  }

#pragma unroll
  for (int r = 0; r < 8; r++) {
    int gr = row0 + r0 + r;
    if (gr < M) {
      ushort4 o;
      o.x = f2bf(acc[r].x); o.y = f2bf(acc[r].y);
      o.z = f2bf(acc[r].z); o.w = f2bf(acc[r].w);
      ((ushort4*)out)[(size_t)gr * 32 + c4] = o;
    }
  }
}

// layer-1 GEMM fused with sort pass 1 (dst histogram).
__global__ __launch_bounds__(256) void k_gemm1_hist(const float* __restrict__ H,
                                                    const float* __restrict__ W,
                                                    void* __restrict__ out, int M,
                                                    int nG, const int* __restrict__ ei,
                                                    int E, int EPB, int NPB,
                                                    int* __restrict__ Hist) {
  if ((int)blockIdx.x >= nG) {
    __shared__ int hs[NBUK];
    int tid = threadIdx.x;
    int j = (int)blockIdx.x - nG;
    hs[tid] = 0;
    __syncthreads();
    int e0 = j * EPB;
    int e1 = min(e0 + EPB, E);
    for (int e = e0 + tid; e < e1; e += 256) {
      int d = ei[E + e];
      atomicAdd(&hs[d / NPB], 1);
    }
    __syncthreads();
    Hist[tid * NBLK + j] = hs[tid];
    return;
  }
  gemm128_body0(H, W, out, M, (int)blockIdx.x * 64);
}

// sort pass 2: bucket-grouped scatter (scan3 folded: S local + blk).
__global__ __launch_bounds__(256) void k_scatter(const int* __restrict__ ei, int E,
                                                 int EPB, int NPB,
                                                 const int* __restrict__ S,
                                                 const int* __restrict__ blk,
                                                 int2* __restrict__ sorted) {
  __shared__ int run[NBUK];
  int tid = threadIdx.x;
  int j = blockIdx.x;
  int idx = tid * NBLK + j;
  run[tid] = S[idx] + blk[idx >> 8];
  __syncthreads();
  int e0 = j * EPB;
  int e1 = min(e0 + EPB, E);
  for (int e = e0 + tid; e < e1; e += 256) {
    int s = ei[e];
    int d = ei[E + e];
    int slot = atomicAdd(&run[d / NPB], 1);
    sorted[slot] = make_int2(s, d);
  }
}

// sort pass 3: per-bucket finalize -> rp, dis, csr.
__global__ __launch_bounds__(256) void k_finalize(const int2* __restrict__ sorted,
                                                  const int* __restrict__ S,
                                                  const int* __restrict__ blk,
                                                  int E, int M, int NPB,
                                                  int* __restrict__ rp,
                                                  float* __restrict__ dis,
                                                  int* __restrict__ csr) {
  __shared__ int cnt[256];
  __shared__ int sc[256];
  int b = blockIdx.x;
  int tid = threadIdx.x;
  int node0 = b * NPB;
  int i0 = b * NBLK;
  int start = S[i0] + blk[i0 >> 8];
  int end;
  if (b == NBUK - 1) end = E;
  else {
    int i1 = i0 + NBLK;
    end = S[i1] + blk[i1 >> 8];
  }
  cnt[tid] = 0;
  __syncthreads();
  for (int i = start + tid; i < end; i += 256) {
    atomicAdd(&cnt[sorted[i].y - node0], 1);
  }
  __syncthreads();
  int v = cnt[tid];
  sc[tid] = v;
  __syncthreads();
  for (int off = 1; off < 256; off <<= 1) {
    int t = (tid >= off) ? sc[tid - off] : 0;
    __syncthreads();
    sc[tid] += t;
    __syncthreads();
  }
  int lrp = sc[tid] - v;
  int node = node0 + tid;
  if (tid < NPB && node < M) {
    rp[node] = start + lrp;
    dis[node] = rsqrtf((float)v + 1.0f);
  }
  if (b == NBUK - 1 && tid == 0) rp[M] = E;
  __syncthreads();
  cnt[tid] = lrp;
  __syncthreads();
  for (int i = start + tid; i < end; i += 256) {
    int2 p = sorted[i];
    int slot = atomicAdd(&cnt[p.y - node0], 1);
    csr[start + slot] = p.x;
  }
}

// ---------------- fused aggregation + GEMM (1024 threads / 16 waves) -------
// Phase A: 16 waves x 4 nodes: h_row = relu(dis_i*(sum dis_s*g_s + dis_i*g_i)+bagg)
//          -> LDS tile Hs[64][128] fp32
// Phase B (FINAL=0): g_out = bf16(Hs @ W)           [out: ushort, M x 128]
// Phase B (FINAL=1): t = Hs@W + bW (t -> LDS); out = t@W2 + bW2  [out: float, M x 64]

template <int FINAL>
__global__ __launch_bounds__(1024) void k_fused(const unsigned short* __restrict__ gin,
                                                const int* __restrict__ csr,
                                                const int* __restrict__ rp,
                                                const float* __restrict__ dis,
                                                const float* __restrict__ bagg,
                                                const float* __restrict__ W,
                                                const float* __restrict__ bW,
                                                const float* __restrict__ W2,
                                                const float* __restrict__ bW2,
                                                void* __restrict__ out, int M) {
  __shared__ float4 Hs[64 * 32];  // 32 KB
  float2* Hs2 = (float2*)Hs;
  int tid = threadIdx.x;
  int lane = tid & 63;
  int w = tid >> 6;  // wave 0..15
  int row0 = blockIdx.x * 64;
  const unsigned int* g1 = (const unsigned int*)gin;

  // ---- phase A: aggregate 4 nodes per wave ----
#pragma unroll
  for (int jj = 0; jj < 4; jj++) {
    int j = w * 4 + jj;
    int i = row0 + j;
    float rx = 0.f, ry = 0.f;
    if (i < M) {
      float di = dis[i];
      unsigned int self = g1[(size_t)i * 64 + lane];
      float ax = di * bf_lo(self);
      float ay = di * bf_hi(self);
      int start = rp[i], end = rp[i + 1];
      for (int base = start; base < end; base += 64) {
        int n = end - base;
        if (n > 64) n = 64;
        int idx = 0;
        float dsv = 0.f;
        if (lane < n) {
          idx = csr[base + lane];
          dsv = dis[idx];
        }
        int jx = 0;
        for (; jx + 4 <= n; jx += 4) {
          int s0 = __shfl(idx, jx, 64);
          int s1 = __shfl(idx, jx + 1, 64);
          int s2 = __shfl(idx, jx + 2, 64);
          int s3 = __shfl(idx, jx + 3, 64);
          float d0 = __shfl(dsv, jx, 64);
          float d1 = __shfl(dsv, jx + 1, 64);
          float d2 = __shfl(dsv, jx + 2, 64);
          float d3 = __shfl(dsv, jx + 3, 64);
          unsigned int v0 = g1[(size_t)s0 * 64 + lane];
          unsigned int v1 = g1[(size_t)s1 * 64 + lane];
          unsigned int v2 = g1[(size_t)s2 * 64 + lane];
          unsigned int v3 = g1[(size_t)s3 * 64 + lane];
          ax = fmaf(d0, bf_lo(v0), ax);
          ay = fmaf(d0, bf_hi(v0), ay);
          ax = fmaf(d1, bf_lo(v1), ax);
          ay = fmaf(d1, bf_hi(v1), ay);
          ax = fmaf(d2, bf_lo(v2), ax);
          ay = fmaf(d2, bf_hi(v2), ay);
          ax = fmaf(d3, bf_lo(v3), ax);
          ay = fmaf(d3, bf_hi(v3), ay);
        }
        for (; jx < n; ++jx) {
          int s0 = __shfl(idx, jx, 64);
          float d0 = __shfl(dsv, jx, 64);
          unsigned int v = g1[(size_t)s0 * 64 + lane];
          ax = fmaf(d0, bf_lo(v), ax);
          ay = fmaf(d0, bf_hi(v), ay);
        }
      }
      float2 b = ((const float2*)bagg)[lane];
      rx = fmaxf(fmaf(di, ax, b.x), 0.f);
      ry = fmaxf(fmaf(di, ay, b.y), 0.f);
    }
    Hs2[j * 64 + lane] = make_float2(rx, ry);  // row j, cols 2*lane..2*lane+1
  }
  __syncthreads();

  // ---- phase B1: Hs @ W  (1024 threads: 2 rows x 4 cols each) ----
  int c4 = tid & 31;          // float4 col group
  int r0 = (tid >> 5) * 2;    // 32 row groups x 2 rows
  const float4* W4 = (const float4*)W;
  float4 acc[2];
  acc[0] = make_float4(0.f, 0.f, 0.f, 0.f);
  acc[1] = make_float4(0.f, 0.f, 0.f, 0.f);

  for (int k4 = 0; k4 < 32; k4++) {
    float4 w0 = W4[(k4 * 4 + 0) * 32 + c4];
    float4 w1 = W4[(k4 * 4 + 1) * 32 + c4];
    float4 w2 = W4[(k4 * 4 + 2) * 32 + c4];
    float4 w3 = W4[(k4 * 4 + 3) * 32 + c4];
#pragma unroll
    for (int r = 0; r < 2; r++) {
      float4 h = Hs[(r0 + r) * 32 + k4];
      acc[r].x = fmaf(h.w, w3.x, fmaf(h.z, w2.x, fmaf(h.y, w1.x, fmaf(h.x, w0.x, acc[r].x))));
      acc[r].y = fmaf(h.w, w3.y, fmaf(h.z, w2.y, fmaf(h.y, w1.y, fmaf(h.x, w0.y, acc[r].y))));
      acc[r].z = fmaf(h.w, w3.z, fmaf(h.z, w2.z, fmaf(h.y, w1.z, fmaf(h.x, w0.z, acc[r].z))));
      acc[r].w = fmaf(h.w, w3.w, fmaf(h.z, w2.w, fmaf(h.y, w1.w, fmaf(h.x, w0.w, acc[r].w))));
    }
  }

  if (!FINAL) {
#pragma unroll
    for (int r = 0; r < 2; r++) {
      int gr = row0 + r0 + r;
      if (gr < M) {
        ushort4 o;
        o.x = f2bf(acc[r].x); o.y = f2bf(acc[r].y);
        o.z = f2bf(acc[r].z); o.w = f2bf(acc[r].w);
        ((ushort4*)out)[(size_t)gr * 32 + c4] = o;
      }
    }
  } else {
    // t = acc + bW -> back into Hs (all Hs reads done; barrier first)
    float4 bv = ((const float4*)bW)[c4];
    __syncthreads();
#pragma unroll
    for (int r = 0; r < 2; r++) {
      float4 v = acc[r];
      v.x += bv.x; v.y += bv.y; v.z += bv.z; v.w += bv.w;
      Hs[(r0 + r) * 32 + c4] = v;
    }
    __syncthreads();

    // ---- phase B2: t @ W2 + bW2 -> out fp32 [M][64] (1 row x 4 cols) ----
    int c42 = tid & 15;       // 16 col groups x 4 = 64 cols
    int r02 = tid >> 4;       // 64 rows
    const float4* V4 = (const float4*)W2;
    float4 a2 = make_float4(0.f, 0.f, 0.f, 0.f);

    for (int k4 = 0; k4 < 32; k4++) {
      float4 w0 = V4[(k4 * 4 + 0) * 16 + c42];
      float4 w1 = V4[(k4 * 4 + 1) * 16 + c42];
      float4 w2v = V4[(k4 * 4 + 2) * 16 + c42];
      float4 w3 = V4[(k4 * 4 + 3) * 16 + c42];
      float4 h = Hs[r02 * 32 + k4];
      a2.x = fmaf(h.w, w3.x, fmaf(h.z, w2v.x, fmaf(h.y, w1.x, fmaf(h.x, w0.x, a2.x))));
      a2.y = fmaf(h.w, w3.y, fmaf(h.z, w2v.y, fmaf(h.y, w1.y, fmaf(h.x, w0.y, a2.y))));
      a2.z = fmaf(h.w, w3.z, fmaf(h.z, w2v.z, fmaf(h.y, w1.z, fmaf(h.x, w0.z, a2.z))));
      a2.w = fmaf(h.w, w3.w, fmaf(h.z, w2v.w, fmaf(h.y, w1.w, fmaf(h.x, w0.w, a2.w))));
    }
    float4 b2v = ((const float4*)bW2)[c42];
    int gr = row0 + r02;
    if (gr < M) {
      a2.x += b2v.x; a2.y += b2v.y; a2.z += b2v.z; a2.w += b2v.w;
      ((float4*)out)[(size_t)gr * 16 + c42] = a2;
    }
  }
}

// ---------------- launch ----------------

extern "C" void kernel_launch(void* const* d_in, const int* in_sizes, int n_in,
                              void* d_out, int out_size, void* d_ws, size_t ws_size,
                              hipStream_t stream) {
  const float* x = (const float*)d_in[0];
  const int* ei = (const int*)d_in[1];
  const float* W1 = (const float*)d_in[2];
  const float* b1 = (const float*)d_in[3];
  const float* W2 = (const float*)d_in[4];
  const float* b2 = (const float*)d_in[5];
  const float* W3 = (const float*)d_in[6];
  const float* b3 = (const float*)d_in[7];
  const float* Wo1 = (const float*)d_in[8];
  const float* bo1 = (const float*)d_in[9];
  const float* Wo2 = (const float*)d_in[10];
  const float* bo2 = (const float*)d_in[11];
  float* out = (float*)d_out;

  int M = in_sizes[0] / DHID;  // 50000
  int E = in_sizes[1] / 2;     // 800000

  int NPB = (M + NBUK - 1) / NBUK;  // nodes per bucket (196)
  int EPB = (E + NBLK - 1) / NBLK;  // edges per sort block
  int SCN = NBUK * NBLK;            // 50176

  // workspace layout (~41.4 MB peak)
  char* ws = (char*)d_ws;
  float* dis = (float*)(ws + 0);                        // M floats
  int* rp = (int*)(ws + (1ull << 20));                  // M+1 ints
  int* Hist = (int*)(ws + (2ull << 20));                // SCN ints
  int* S = (int*)(ws + (3ull << 20));                   // SCN ints
  int* blk = (int*)(ws + (4ull << 20));                 // <=256 ints
  int* csr = (int*)(ws + (5ull << 20));                 // E ints (3.2 MB)
  unsigned short* gA = (unsigned short*)(ws + (9ull << 20));   // M*128 bf16 (12.8 MB)
  unsigned short* gB = (unsigned short*)(ws + (22ull << 20));  // M*128 bf16 (12.8 MB)
  int2* sorted = (int2*)(ws + (35ull << 20));           // E int2 (6.4 MB)

  int gG = (M + 63) / 64;  // 782

  // layer-1 GEMM fused with sort pass 1
  k_gemm1_hist<<<gG + NBLK, 256, 0, stream>>>(x, W1, gA, M, gG, ei, E, EPB, NPB, Hist);
  // scan Hist
  k_scan1<<<NBLK, 256, 0, stream>>>(Hist, S, blk, SCN);
  k_scan2<<<1, 256, 0, stream>>>(blk, NBLK);
  // sort pass 2 + 3 (scan3 folded in)
  k_scatter<<<NBLK, 256, 0, stream>>>(ei, E, EPB, NPB, S, blk, sorted);
  k_finalize<<<NBUK, 256, 0, stream>>>(sorted, S, blk, E, M, NPB, rp, dis, csr);

  // fused layers (1024-thread blocks)
  k_fused<0><<<gG, 1024, 0, stream>>>(gA, csr, rp, dis, b1, W2, nullptr, nullptr,
                                      nullptr, gB, M);
  k_fused<0><<<gG, 1024, 0, stream>>>(gB, csr, rp, dis, b2, W3, nullptr, nullptr,
                                      nullptr, gA, M);
  k_fused<1><<<gG, 1024, 0, stream>>>(gA, csr, rp, dis, b3, Wo1, bo1, Wo2, bo2,
                                      out, M);
}

// Round 6
// 1411.315 us; speedup vs baseline: 2.2069x; 2.2069x over previous
//
#include <hip/hip_runtime.h>

// GCN 3-layer + MLP head.
// Round-6 change: k_fused uses 16-row tiles, 256 threads, grid=3125 blocks.
// Round-5's 1024-thread blocks made the compiler cap VGPRs at 64 -> per-edge
// scratch spills (WRITE_SIZE 1.68GB for a 12.8MB output, VALUBusy 1.8%).
// Occupancy now comes from block count: ~8 blocks/CU x 4 waves = 32 waves/CU
// during the gather phase, VGPR unconstrained (launch_bounds(256) only).
// Pipeline (8 launches):
//   k_gemm1_hist: g1 = bf16(x@W1), fused with dst-histogram
//   scan1/scan2 ; scatter ; finalize  -> csr, rp, dis
//   k_fused<0>(g1,b1,W2) -> g2 ; k_fused<0>(g2,b2,W3) -> g3
//   k_fused<1>(g3,b3,Wo1,bo1,Wo2,bo2) -> out
// Math: h_i = relu(dis_i*( sum_{e:dst=i} dis_src*graw_src + dis_i*graw_i )+b)
// graw = h@W stored bf16; all accumulation fp32.

#define DHID 128
#define NBUK 256   // dst buckets
#define NBLK 196   // edge-chunk blocks (NBUK*NBLK = 50176 scan elements)
#define FROWS 16   // fused-kernel tile rows

static __device__ __forceinline__ unsigned short f2bf(float f) {
  unsigned int u = __float_as_uint(f);
  u += 0x7fffu + ((u >> 16) & 1u);  // round-to-nearest-even
  return (unsigned short)(u >> 16);
}
static __device__ __forceinline__ float bf_lo(unsigned int v) {
  return __uint_as_float(v << 16);
}
static __device__ __forceinline__ float bf_hi(unsigned int v) {
  return __uint_as_float(v & 0xffff0000u);
}

// ---------------- scan ----------------

__global__ __launch_bounds__(256) void k_scan1(const int* __restrict__ in,
                                               int* __restrict__ out,
                                               int* __restrict__ blk, int Mtot) {
  __shared__ int s[256];
  int tid = threadIdx.x;
  int i = blockIdx.x * 256 + tid;
  int v = (i < Mtot) ? in[i] : 0;
  s[tid] = v;
  __syncthreads();
  for (int off = 1; off < 256; off <<= 1) {
    int t = (tid >= off) ? s[tid - off] : 0;
    __syncthreads();
    s[tid] += t;
    __syncthreads();
  }
  if (i < Mtot) out[i] = s[tid] - v;  // exclusive within block
  if (tid == 255) blk[blockIdx.x] = s[255];
}

__global__ void k_scan2(int* blk, int n) {  // n <= 256
  __shared__ int s[256];
  int tid = threadIdx.x;
  int v = (tid < n) ? blk[tid] : 0;
  s[tid] = v;
  __syncthreads();
  for (int off = 1; off < 256; off <<= 1) {
    int t = (tid >= off) ? s[tid - off] : 0;
    __syncthreads();
    s[tid] += t;
    __syncthreads();
  }
  if (tid < n) blk[tid] = s[tid] - v;  // exclusive
}

// ---------------- GEMM body: [64,128] @ [128,128] -> bf16 (hist kernel) ----

__device__ __forceinline__ void gemm128_body0(const float* __restrict__ H,
                                              const float* __restrict__ W,
                                              void* __restrict__ out, int M,
                                              int row0) {
  __shared__ float4 Hs[64 * 32];  // 32 KB
  int tid = threadIdx.x;
  const float4* H4 = (const float4*)H;
#pragma unroll
  for (int i = 0; i < 8; i++) {
    int slot = tid + i * 256;  // 0..2047
    int r = slot >> 5, c4 = slot & 31;
    int gr = row0 + r;
    Hs[slot] = (gr < M) ? H4[(size_t)gr * 32 + c4] : make_float4(0.f, 0.f, 0.f, 0.f);
  }
  __syncthreads();

  int c4 = tid & 31;
  int r0 = (tid >> 5) * 8;
  const float4* W4 = (const float4*)W;
  float4 acc[8];
#pragma unroll
  for (int r = 0; r < 8; r++) acc[r] = make_float4(0.f, 0.f, 0.f, 0.f);

  for (int k4 = 0; k4 < 32; k4++) {
    float4 w0 = W4[(k4 * 4 + 0) * 32 + c4];
    float4 w1 = W4[(k4 * 4 + 1) * 32 + c4];
    float4 w2 = W4[(k4 * 4 + 2) * 32 + c4];
    float4 w3 = W4[(k4 * 4 + 3) * 32 + c4];
#pragma unroll
    for (int r = 0; r < 8; r++) {
      float4 h = Hs[(r0 + r) * 32 + k4];
      acc[r].x = fmaf(h.w, w3.x, fmaf(h.z, w2.x, fmaf(h.y, w1.x, fmaf(h.x, w0.x, acc[r].x))));
      acc[r].y = fmaf(h.w, w3.y, fmaf(h.z, w2.y, fmaf(h.y, w1.y, fmaf(h.x, w0.y, acc[r].y))));
      acc[r].z = fmaf(h.w, w3.z, fmaf(h.z, w2.z, fmaf(h.y, w1.z, fmaf(h.x, w0.z, acc[r].z))));
      acc[r].w = fmaf(h.w, w3.w, fmaf(h.z, w2.w, fmaf(h.y, w1.w, fmaf(h.x, w0.w, acc[r].w))));
    }
  }

#pragma unroll
  for (int r = 0; r < 8; r++) {
    int gr = row0 + r0 + r;
    if (gr < M) {
      ushort4 o;
      o.x = f2bf(acc[r].x); o.y = f2bf(acc[r].y);
      o.z = f2bf(acc[r].z); o.w = f2bf(acc[r].w);
      ((ushort4*)out)[(size_t)gr * 32 + c4] = o;
    }
  }
}

// layer-1 GEMM fused with sort pass 1 (dst histogram).
__global__ __launch_bounds__(256) void k_gemm1_hist(const float* __restrict__ H,
                                                    const float* __restrict__ W,
                                                    void* __restrict__ out, int M,
                                                    int nG, const int* __restrict__ ei,
                                                    int E, int EPB, int NPB,
                                                    int* __restrict__ Hist) {
  if ((int)blockIdx.x >= nG) {
    __shared__ int hs[NBUK];
    int tid = threadIdx.x;
    int j = (int)blockIdx.x - nG;
    hs[tid] = 0;
    __syncthreads();
    int e0 = j * EPB;
    int e1 = min(e0 + EPB, E);
    for (int e = e0 + tid; e < e1; e += 256) {
      int d = ei[E + e];
      atomicAdd(&hs[d / NPB], 1);
    }
    __syncthreads();
    Hist[tid * NBLK + j] = hs[tid];
    return;
  }
  gemm128_body0(H, W, out, M, (int)blockIdx.x * 64);
}

// sort pass 2: bucket-grouped scatter (scan3 folded: S local + blk).
__global__ __launch_bounds__(256) void k_scatter(const int* __restrict__ ei, int E,
                                                 int EPB, int NPB,
                                                 const int* __restrict__ S,
                                                 const int* __restrict__ blk,
                                                 int2* __restrict__ sorted) {
  __shared__ int run[NBUK];
  int tid = threadIdx.x;
  int j = blockIdx.x;
  int idx = tid * NBLK + j;
  run[tid] = S[idx] + blk[idx >> 8];
  __syncthreads();
  int e0 = j * EPB;
  int e1 = min(e0 + EPB, E);
  for (int e = e0 + tid; e < e1; e += 256) {
    int s = ei[e];
    int d = ei[E + e];
    int slot = atomicAdd(&run[d / NPB], 1);
    sorted[slot] = make_int2(s, d);
  }
}

// sort pass 3: per-bucket finalize -> rp, dis, csr.
__global__ __launch_bounds__(256) void k_finalize(const int2* __restrict__ sorted,
                                                  const int* __restrict__ S,
                                                  const int* __restrict__ blk,
                                                  int E, int M, int NPB,
                                                  int* __restrict__ rp,
                                                  float* __restrict__ dis,
                                                  int* __restrict__ csr) {
  __shared__ int cnt[256];
  __shared__ int sc[256];
  int b = blockIdx.x;
  int tid = threadIdx.x;
  int node0 = b * NPB;
  int i0 = b * NBLK;
  int start = S[i0] + blk[i0 >> 8];
  int end;
  if (b == NBUK - 1) end = E;
  else {
    int i1 = i0 + NBLK;
    end = S[i1] + blk[i1 >> 8];
  }
  cnt[tid] = 0;
  __syncthreads();
  for (int i = start + tid; i < end; i += 256) {
    atomicAdd(&cnt[sorted[i].y - node0], 1);
  }
  __syncthreads();
  int v = cnt[tid];
  sc[tid] = v;
  __syncthreads();
  for (int off = 1; off < 256; off <<= 1) {
    int t = (tid >= off) ? sc[tid - off] : 0;
    __syncthreads();
    sc[tid] += t;
    __syncthreads();
  }
  int lrp = sc[tid] - v;
  int node = node0 + tid;
  if (tid < NPB && node < M) {
    rp[node] = start + lrp;
    dis[node] = rsqrtf((float)v + 1.0f);
  }
  if (b == NBUK - 1 && tid == 0) rp[M] = E;
  __syncthreads();
  cnt[tid] = lrp;
  __syncthreads();
  for (int i = start + tid; i < end; i += 256) {
    int2 p = sorted[i];
    int slot = atomicAdd(&cnt[p.y - node0], 1);
    csr[start + slot] = p.x;
  }
}

// ---------------- fused aggregation + GEMM (16-row tile, 256 threads) ------
// Phase A: 4 waves x 4 nodes: h_row = relu(dis_i*(sum dis_s*g_s + dis_i*g_i)+bagg)
//          -> LDS tile Hs[16][128] fp32 (8 KB)
// Phase B (FINAL=0): g_out = bf16(Hs @ W)           [out: ushort, M x 128]
// Phase B (FINAL=1): t = Hs@W + bW (t -> LDS); out = t@W2 + bW2  [out: float, M x 64]

template <int FINAL>
__global__ __launch_bounds__(256) void k_fused(const unsigned short* __restrict__ gin,
                                               const int* __restrict__ csr,
                                               const int* __restrict__ rp,
                                               const float* __restrict__ dis,
                                               const float* __restrict__ bagg,
                                               const float* __restrict__ W,
                                               const float* __restrict__ bW,
                                               const float* __restrict__ W2,
                                               const float* __restrict__ bW2,
                                               void* __restrict__ out, int M) {
  __shared__ float4 Hs[FROWS * 32];  // 8 KB
  float2* Hs2 = (float2*)Hs;
  int tid = threadIdx.x;
  int lane = tid & 63;
  int w = tid >> 6;  // wave 0..3
  int row0 = blockIdx.x * FROWS;
  const unsigned int* g1 = (const unsigned int*)gin;

  // ---- phase A: aggregate 4 nodes per wave (loop rolled: keep VGPR low) ----
  for (int jj = 0; jj < 4; jj++) {
    int j = w * 4 + jj;
    int i = row0 + j;
    float rx = 0.f, ry = 0.f;
    if (i < M) {
      float di = dis[i];
      unsigned int self = g1[(size_t)i * 64 + lane];
      float ax = di * bf_lo(self);
      float ay = di * bf_hi(self);
      int start = rp[i], end = rp[i + 1];
      for (int base = start; base < end; base += 64) {
        int n = end - base;
        if (n > 64) n = 64;
        int idx = 0;
        float dsv = 0.f;
        if (lane < n) {
          idx = csr[base + lane];
          dsv = dis[idx];
        }
        int jx = 0;
        for (; jx + 4 <= n; jx += 4) {
          int s0 = __shfl(idx, jx, 64);
          int s1 = __shfl(idx, jx + 1, 64);
          int s2 = __shfl(idx, jx + 2, 64);
          int s3 = __shfl(idx, jx + 3, 64);
          float d0 = __shfl(dsv, jx, 64);
          float d1 = __shfl(dsv, jx + 1, 64);
          float d2 = __shfl(dsv, jx + 2, 64);
          float d3 = __shfl(dsv, jx + 3, 64);
          unsigned int v0 = g1[(size_t)s0 * 64 + lane];
          unsigned int v1 = g1[(size_t)s1 * 64 + lane];
          unsigned int v2 = g1[(size_t)s2 * 64 + lane];
          unsigned int v3 = g1[(size_t)s3 * 64 + lane];
          ax = fmaf(d0, bf_lo(v0), ax);
          ay = fmaf(d0, bf_hi(v0), ay);
          ax = fmaf(d1, bf_lo(v1), ax);
          ay = fmaf(d1, bf_hi(v1), ay);
          ax = fmaf(d2, bf_lo(v2), ax);
          ay = fmaf(d2, bf_hi(v2), ay);
          ax = fmaf(d3, bf_lo(v3), ax);
          ay = fmaf(d3, bf_hi(v3), ay);
        }
        for (; jx < n; ++jx) {
          int s0 = __shfl(idx, jx, 64);
          float d0 = __shfl(dsv, jx, 64);
          unsigned int v = g1[(size_t)s0 * 64 + lane];
          ax = fmaf(d0, bf_lo(v), ax);
          ay = fmaf(d0, bf_hi(v), ay);
        }
      }
      float2 b = ((const float2*)bagg)[lane];
      rx = fmaxf(fmaf(di, ax, b.x), 0.f);
      ry = fmaxf(fmaf(di, ay, b.y), 0.f);
    }
    Hs2[j * 64 + lane] = make_float2(rx, ry);  // row j, cols 2*lane..2*lane+1
  }
  __syncthreads();

  // ---- phase B1: Hs @ W  (256 threads: 2 rows x 4 cols each) ----
  int c4 = tid & 31;          // float4 col group
  int r0 = (tid >> 5) * 2;    // 8 row groups x 2 rows = 16 rows
  const float4* W4 = (const float4*)W;
  float4 acc[2];
  acc[0] = make_float4(0.f, 0.f, 0.f, 0.f);
  acc[1] = make_float4(0.f, 0.f, 0.f, 0.f);

  for (int k4 = 0; k4 < 32; k4++) {
    float4 w0 = W4[(k4 * 4 + 0) * 32 + c4];
    float4 w1 = W4[(k4 * 4 + 1) * 32 + c4];
    float4 w2 = W4[(k4 * 4 + 2) * 32 + c4];
    float4 w3 = W4[(k4 * 4 + 3) * 32 + c4];
#pragma unroll
    for (int r = 0; r < 2; r++) {
      float4 h = Hs[(r0 + r) * 32 + k4];
      acc[r].x = fmaf(h.w, w3.x, fmaf(h.z, w2.x, fmaf(h.y, w1.x, fmaf(h.x, w0.x, acc[r].x))));
      acc[r].y = fmaf(h.w, w3.y, fmaf(h.z, w2.y, fmaf(h.y, w1.y, fmaf(h.x, w0.y, acc[r].y))));
      acc[r].z = fmaf(h.w, w3.z, fmaf(h.z, w2.z, fmaf(h.y, w1.z, fmaf(h.x, w0.z, acc[r].z))));
      acc[r].w = fmaf(h.w, w3.w, fmaf(h.z, w2.w, fmaf(h.y, w1.w, fmaf(h.x, w0.w, acc[r].w))));
    }
  }

  if (!FINAL) {
#pragma unroll
    for (int r = 0; r < 2; r++) {
      int gr = row0 + r0 + r;
      if (gr < M) {
        ushort4 o;
        o.x = f2bf(acc[r].x); o.y = f2bf(acc[r].y);
        o.z = f2bf(acc[r].z); o.w = f2bf(acc[r].w);
        ((ushort4*)out)[(size_t)gr * 32 + c4] = o;
      }
    }
  } else {
    // t = acc + bW -> back into Hs (all Hs reads done; barrier first)
    float4 bv = ((const float4*)bW)[c4];
    __syncthreads();
#pragma unroll
    for (int r = 0; r < 2; r++) {
      float4 v = acc[r];
      v.x += bv.x; v.y += bv.y; v.z += bv.z; v.w += bv.w;
      Hs[(r0 + r) * 32 + c4] = v;
    }
    __syncthreads();

    // ---- phase B2: t @ W2 + bW2 -> out fp32 [M][64] (1 row x 4 cols) ----
    int c42 = tid & 15;       // 16 col groups x 4 = 64 cols
    int r02 = tid >> 4;       // 16 rows
    const float4* V4 = (const float4*)W2;
    float4 a2 = make_float4(0.f, 0.f, 0.f, 0.f);

    for (int k4 = 0; k4 < 32; k4++) {
      float4 w0 = V4[(k4 * 4 + 0) * 16 + c42];
      float4 w1 = V4[(k4 * 4 + 1) * 16 + c42];
      float4 w2v = V4[(k4 * 4 + 2) * 16 + c42];
      float4 w3 = V4[(k4 * 4 + 3) * 16 + c42];
      float4 h = Hs[r02 * 32 + k4];
      a2.x = fmaf(h.w, w3.x, fmaf(h.z, w2v.x, fmaf(h.y, w1.x, fmaf(h.x, w0.x, a2.x))));
      a2.y = fmaf(h.w, w3.y, fmaf(h.z, w2v.y, fmaf(h.y, w1.y, fmaf(h.x, w0.y, a2.y))));
      a2.z = fmaf(h.w, w3.z, fmaf(h.z, w2v.z, fmaf(h.y, w1.z, fmaf(h.x, w0.z, a2.z))));
      a2.w = fmaf(h.w, w3.w, fmaf(h.z, w2v.w, fmaf(h.y, w1.w, fmaf(h.x, w0.w, a2.w))));
    }
    float4 b2v = ((const float4*)bW2)[c42];
    int gr = row0 + r02;
    if (gr < M) {
      a2.x += b2v.x; a2.y += b2v.y; a2.z += b2v.z; a2.w += b2v.w;
      ((float4*)out)[(size_t)gr * 16 + c42] = a2;
    }
  }
}

// ---------------- launch ----------------

extern "C" void kernel_launch(void* const* d_in, const int* in_sizes, int n_in,
                              void* d_out, int out_size, void* d_ws, size_t ws_size,
                              hipStream_t stream) {
  const float* x = (const float*)d_in[0];
  const int* ei = (const int*)d_in[1];
  const float* W1 = (const float*)d_in[2];
  const float* b1 = (const float*)d_in[3];
  const float* W2 = (const float*)d_in[4];
  const float* b2 = (const float*)d_in[5];
  const float* W3 = (const float*)d_in[6];
  const float* b3 = (const float*)d_in[7];
  const float* Wo1 = (const float*)d_in[8];
  const float* bo1 = (const float*)d_in[9];
  const float* Wo2 = (const float*)d_in[10];
  const float* bo2 = (const float*)d_in[11];
  float* out = (float*)d_out;

  int M = in_sizes[0] / DHID;  // 50000
  int E = in_sizes[1] / 2;     // 800000

  int NPB = (M + NBUK - 1) / NBUK;  // nodes per bucket (196)
  int EPB = (E + NBLK - 1) / NBLK;  // edges per sort block
  int SCN = NBUK * NBLK;            // 50176

  // workspace layout (~41.4 MB peak)
  char* ws = (char*)d_ws;
  float* dis = (float*)(ws + 0);                        // M floats
  int* rp = (int*)(ws + (1ull << 20));                  // M+1 ints
  int* Hist = (int*)(ws + (2ull << 20));                // SCN ints
  int* S = (int*)(ws + (3ull << 20));                   // SCN ints
  int* blk = (int*)(ws + (4ull << 20));                 // <=256 ints
  int* csr = (int*)(ws + (5ull << 20));                 // E ints (3.2 MB)
  unsigned short* gA = (unsigned short*)(ws + (9ull << 20));   // M*128 bf16 (12.8 MB)
  unsigned short* gB = (unsigned short*)(ws + (22ull << 20));  // M*128 bf16 (12.8 MB)
  int2* sorted = (int2*)(ws + (35ull << 20));           // E int2 (6.4 MB)

  int gG = (M + 63) / 64;      // 782 (hist/gemm1 tiles)
  int gF = (M + FROWS - 1) / FROWS;  // 3125 (fused tiles)

  // layer-1 GEMM fused with sort pass 1
  k_gemm1_hist<<<gG + NBLK, 256, 0, stream>>>(x, W1, gA, M, gG, ei, E, EPB, NPB, Hist);
  // scan Hist
  k_scan1<<<NBLK, 256, 0, stream>>>(Hist, S, blk, SCN);
  k_scan2<<<1, 256, 0, stream>>>(blk, NBLK);
  // sort pass 2 + 3 (scan3 folded in)
  k_scatter<<<NBLK, 256, 0, stream>>>(ei, E, EPB, NPB, S, blk, sorted);
  k_finalize<<<NBUK, 256, 0, stream>>>(sorted, S, blk, E, M, NPB, rp, dis, csr);

  // fused layers (16-row tiles, 256 threads)
  k_fused<0><<<gF, 256, 0, stream>>>(gA, csr, rp, dis, b1, W2, nullptr, nullptr,
                                     nullptr, gB, M);
  k_fused<0><<<gF, 256, 0, stream>>>(gB, csr, rp, dis, b2, W3, nullptr, nullptr,
                                     nullptr, gA, M);
  k_fused<1><<<gF, 256, 0, stream>>>(gA, csr, rp, dis, b3, Wo1, bo1, Wo2, bo2,
                                     out, M);
}

// Round 8
// 199.381 us; speedup vs baseline: 15.6212x; 7.0785x over previous
//
#include <hip/hip_runtime.h>

// GCN 3-layer + MLP head. Round-8: FIX round-7's workspace overlap —
// csr (5MiB + 3.2MB = ends 8.45MiB) overlapped W1t/W2t at 8MiB; k_finalize
// clobbered W2t with edge-index ints, and indices in [32640,32767] are bf16
// Inf/NaN bit patterns (0x7F80-0x7FFF) -> NaN through layers 2+. Weights now
// live at 4MiB+64KB (clear of everything). No other changes vs round 7.
//   k_prep: weights -> bf16 transposed Wt[col][k]
//   k_mgemm: 64-row tile, LDS-staged A+Wt (row pad +8 shorts, 272B stride),
//            v_mfma_f32_16x16x32_bf16, 4 K-steps x NCOLS/16 col-tiles.
//   k_agg emits h in bf16 (feeds bf16 GEMM A directly).
// Fragment mapping (AMD docs + m89-verified C/D; A/B use identical k-order
// so any hw k-permutation cancels in the dot product):
//   A: row=l&15, k=(l>>4)*8+j ; B: col=l&15, k=(l>>4)*8+j
//   C/D: col=l&15, row=(l>>4)*4+r
// Math: h_i = relu(dis_i*( sum_{e:dst=i} dis_src*g_src + dis_i*g_i )+b),
// g = h@W bf16; fp32 accumulation everywhere.

#define DHID 128
#define NBUK 256   // dst buckets
#define NBLK 196   // edge-chunk blocks (NBUK*NBLK = 50176 scan elements)

typedef __attribute__((ext_vector_type(8))) short bf16x8;
typedef __attribute__((ext_vector_type(4))) float f32x4;

static __device__ __forceinline__ unsigned short f2bf(float f) {
  unsigned int u = __float_as_uint(f);
  u += 0x7fffu + ((u >> 16) & 1u);  // round-to-nearest-even
  return (unsigned short)(u >> 16);
}
static __device__ __forceinline__ float bf_lo(unsigned int v) {
  return __uint_as_float(v << 16);
}
static __device__ __forceinline__ float bf_hi(unsigned int v) {
  return __uint_as_float(v & 0xffff0000u);
}

// ---------------- weight prep: fp32 [K=128][N] -> bf16 Wt[N][128] ----------
__global__ __launch_bounds__(256) void k_prep(const float* __restrict__ W1,
                                              const float* __restrict__ W2,
                                              const float* __restrict__ W3,
                                              const float* __restrict__ Wo1,
                                              const float* __restrict__ Wo2,
                                              unsigned short* __restrict__ W1t,
                                              unsigned short* __restrict__ W2t,
                                              unsigned short* __restrict__ W3t,
                                              unsigned short* __restrict__ Wo1t,
                                              unsigned short* __restrict__ Wo2t) {
  int b = blockIdx.x;  // 40 blocks: 8 per weight
  int wi = b >> 3, part = b & 7;
  const float* src;
  unsigned short* dst;
  int N;
  switch (wi) {
    case 0: src = W1; dst = W1t; N = 128; break;
    case 1: src = W2; dst = W2t; N = 128; break;
    case 2: src = W3; dst = W3t; N = 128; break;
    case 3: src = Wo1; dst = Wo1t; N = 128; break;
    default: src = Wo2; dst = Wo2t; N = 64; break;
  }
  int cpp = N >> 3;  // cols per part
  int c0 = part * cpp;
  for (int idx = threadIdx.x; idx < cpp * 128; idx += 256) {
    int c = c0 + (idx >> 7);
    int k = idx & 127;
    dst[c * 128 + k] = f2bf(src[(size_t)k * N + c]);  // write coalesced
  }
}

// ---------------- MFMA GEMM body: [64,128] @ Wt^T -> out -------------------
// OMODE 0: bf16 out, no bias; 1: bf16 out + bias; 2: fp32 out + bias (N=64)
template <int NCOLS, int INF32, int OMODE>
__device__ __forceinline__ void mgemm_body(const void* __restrict__ Hsrc,
                                           const unsigned short* __restrict__ Wt,
                                           const float* __restrict__ bias,
                                           void* __restrict__ out, int M,
                                           int row0) {
  __shared__ unsigned short As[64][136];      // +8 pad: 272B stride
  __shared__ unsigned short Ws[NCOLS][136];
  int tid = threadIdx.x;

  // stage A tile (64 rows x 128 bf16)
  {
    int row = tid >> 2;   // 0..63
    int seg = tid & 3;    // 32 shorts each
    int gr = row0 + row;
    if (INF32) {
      const float4* H4 = (const float4*)Hsrc;  // row = 32 float4
#pragma unroll
      for (int i = 0; i < 8; i++) {
        float4 v = (gr < M) ? H4[(size_t)gr * 32 + seg * 8 + i]
                            : make_float4(0.f, 0.f, 0.f, 0.f);
        ushort4 o;
        o.x = f2bf(v.x); o.y = f2bf(v.y); o.z = f2bf(v.z); o.w = f2bf(v.w);
        *(ushort4*)&As[row][seg * 32 + i * 4] = o;
      }
    } else {
      const uint4* H4 = (const uint4*)Hsrc;  // row = 16 uint4 (128 bf16)
#pragma unroll
      for (int i = 0; i < 4; i++) {
        uint4 v = (gr < M) ? H4[(size_t)gr * 16 + seg * 4 + i]
                           : make_uint4(0u, 0u, 0u, 0u);
        *(uint4*)&As[row][seg * 32 + i * 8] = v;
      }
    }
  }
  // stage Wt (NCOLS x 128 bf16 = NCOLS*16 uint4)
  {
    const uint4* Wt4 = (const uint4*)Wt;
    for (int idx = tid; idx < NCOLS * 16; idx += 256) {
      int c = idx >> 4, kk = idx & 15;
      *(uint4*)&Ws[c][kk * 8] = Wt4[idx];
    }
  }
  __syncthreads();

  int l = tid & 63;
  int w = tid >> 6;        // wave 0..3 -> rows w*16..w*16+15
  int mrow = l & 15;
  int kch = (l >> 4) * 8;

  f32x4 acc[NCOLS / 16];
#pragma unroll
  for (int c = 0; c < NCOLS / 16; c++) acc[c] = (f32x4){0.f, 0.f, 0.f, 0.f};

#pragma unroll
  for (int kk = 0; kk < 4; kk++) {
    bf16x8 a = *(const bf16x8*)&As[w * 16 + mrow][kk * 32 + kch];
#pragma unroll
    for (int c = 0; c < NCOLS / 16; c++) {
      bf16x8 b = *(const bf16x8*)&Ws[c * 16 + mrow][kk * 32 + kch];
      acc[c] = __builtin_amdgcn_mfma_f32_16x16x32_bf16(a, b, acc[c], 0, 0, 0);
    }
  }

  int rbase = row0 + w * 16 + (l >> 4) * 4;
#pragma unroll
  for (int c = 0; c < NCOLS / 16; c++) {
    int col = c * 16 + mrow;
    float bv = (OMODE != 0) ? bias[col] : 0.f;
#pragma unroll
    for (int r = 0; r < 4; r++) {
      int gr = rbase + r;
      if (gr < M) {
        float v = acc[c][r] + bv;
        if (OMODE == 2)
          ((float*)out)[(size_t)gr * NCOLS + col] = v;
        else
          ((unsigned short*)out)[(size_t)gr * 128 + col] = f2bf(v);
      }
    }
  }
}

template <int NCOLS, int INF32, int OMODE>
__global__ __launch_bounds__(256) void k_mgemm(const void* __restrict__ H,
                                               const unsigned short* __restrict__ Wt,
                                               const float* __restrict__ bias,
                                               void* __restrict__ out, int M) {
  mgemm_body<NCOLS, INF32, OMODE>(H, Wt, bias, out, M, (int)blockIdx.x * 64);
}

// layer-1 MFMA GEMM (x fp32 -> gA bf16) fused with sort pass 1 (histogram).
__global__ __launch_bounds__(256) void k_gemm1_hist(const float* __restrict__ x,
                                                    const unsigned short* __restrict__ W1t,
                                                    void* __restrict__ out, int M,
                                                    int nG, const int* __restrict__ ei,
                                                    int E, int EPB, int NPB,
                                                    int* __restrict__ Hist) {
  __shared__ int hs[NBUK];
  if ((int)blockIdx.x >= nG) {
    int tid = threadIdx.x;
    int j = (int)blockIdx.x - nG;
    hs[tid] = 0;
    __syncthreads();
    int e0 = j * EPB;
    int e1 = min(e0 + EPB, E);
    for (int e = e0 + tid; e < e1; e += 256) {
      int d = ei[E + e];
      atomicAdd(&hs[d / NPB], 1);
    }
    __syncthreads();
    Hist[tid * NBLK + j] = hs[tid];
    return;
  }
  mgemm_body<128, 1, 0>(x, W1t, nullptr, out, M, (int)blockIdx.x * 64);
}

// ---------------- scan ----------------

__global__ __launch_bounds__(256) void k_scan1(const int* __restrict__ in,
                                               int* __restrict__ out,
                                               int* __restrict__ blk, int Mtot) {
  __shared__ int s[256];
  int tid = threadIdx.x;
  int i = blockIdx.x * 256 + tid;
  int v = (i < Mtot) ? in[i] : 0;
  s[tid] = v;
  __syncthreads();
  for (int off = 1; off < 256; off <<= 1) {
    int t = (tid >= off) ? s[tid - off] : 0;
    __syncthreads();
    s[tid] += t;
    __syncthreads();
  }
  if (i < Mtot) out[i] = s[tid] - v;  // exclusive within block
  if (tid == 255) blk[blockIdx.x] = s[255];
}

__global__ void k_scan2(int* blk, int n) {  // n <= 256
  __shared__ int s[256];
  int tid = threadIdx.x;
  int v = (tid < n) ? blk[tid] : 0;
  s[tid] = v;
  __syncthreads();
  for (int off = 1; off < 256; off <<= 1) {
    int t = (tid >= off) ? s[tid - off] : 0;
    __syncthreads();
    s[tid] += t;
    __syncthreads();
  }
  if (tid < n) blk[tid] = s[tid] - v;  // exclusive
}

// sort pass 2: bucket-grouped scatter (scan3 folded: S local + blk).
__global__ __launch_bounds__(256) void k_scatter(const int* __restrict__ ei, int E,
                                                 int EPB, int NPB,
                                                 const int* __restrict__ S,
                                                 const int* __restrict__ blk,
                                                 int2* __restrict__ sorted) {
  __shared__ int run[NBUK];
  int tid = threadIdx.x;
  int j = blockIdx.x;
  int idx = tid * NBLK + j;
  run[tid] = S[idx] + blk[idx >> 8];
  __syncthreads();
  int e0 = j * EPB;
  int e1 = min(e0 + EPB, E);
  for (int e = e0 + tid; e < e1; e += 256) {
    int s = ei[e];
    int d = ei[E + e];
    int slot = atomicAdd(&run[d / NPB], 1);
    sorted[slot] = make_int2(s, d);
  }
}

// sort pass 3: per-bucket finalize -> rp, dis, csr.
__global__ __launch_bounds__(256) void k_finalize(const int2* __restrict__ sorted,
                                                  const int* __restrict__ S,
                                                  const int* __restrict__ blk,
                                                  int E, int M, int NPB,
                                                  int* __restrict__ rp,
                                                  float* __restrict__ dis,
                                                  int* __restrict__ csr) {
  __shared__ int cnt[256];
  __shared__ int sc[256];
  int b = blockIdx.x;
  int tid = threadIdx.x;
  int node0 = b * NPB;
  int i0 = b * NBLK;
  int start = S[i0] + blk[i0 >> 8];
  int end;
  if (b == NBUK - 1) end = E;
  else {
    int i1 = i0 + NBLK;
    end = S[i1] + blk[i1 >> 8];
  }
  cnt[tid] = 0;
  __syncthreads();
  for (int i = start + tid; i < end; i += 256) {
    atomicAdd(&cnt[sorted[i].y - node0], 1);
  }
  __syncthreads();
  int v = cnt[tid];
  sc[tid] = v;
  __syncthreads();
  for (int off = 1; off < 256; off <<= 1) {
    int t = (tid >= off) ? sc[tid - off] : 0;
    __syncthreads();
    sc[tid] += t;
    __syncthreads();
  }
  int lrp = sc[tid] - v;
  int node = node0 + tid;
  if (tid < NPB && node < M) {
    rp[node] = start + lrp;
    dis[node] = rsqrtf((float)v + 1.0f);
  }
  if (b == NBUK - 1 && tid == 0) rp[M] = E;
  __syncthreads();
  cnt[tid] = lrp;
  __syncthreads();
  for (int i = start + tid; i < end; i += 256) {
    int2 p = sorted[i];
    int slot = atomicAdd(&cnt[p.y - node0], 1);
    csr[start + slot] = p.x;
  }
}

// ---------------- Aggregation: one wave per node, bf16 in/out --------------
// h_out[i] = relu( dis_i*( sum_{e:dst=i} dis_src*g_src + dis_i*g_i ) + b )
__global__ __launch_bounds__(256) void k_agg(const unsigned short* __restrict__ g,
                                             const int* __restrict__ csr,
                                             const int* __restrict__ rp,
                                             const float* __restrict__ dis,
                                             const float* __restrict__ bias,
                                             unsigned short* __restrict__ outh,
                                             int M) {
  int wid = (int)((blockIdx.x * 256 + threadIdx.x) >> 6);  // node id
  int lane = threadIdx.x & 63;
  if (wid >= M) return;
  const unsigned int* g1 = (const unsigned int*)g;  // 2 bf16 per uint
  float di = dis[wid];
  unsigned int self = g1[(size_t)wid * 64 + lane];
  float ax = di * bf_lo(self);
  float ay = di * bf_hi(self);
  int start = rp[wid], end = rp[wid + 1];
  for (int base = start; base < end; base += 64) {
    int n = end - base;
    if (n > 64) n = 64;
    int idx = 0;
    float dsv = 0.f;
    if (lane < n) {
      idx = csr[base + lane];
      dsv = dis[idx];
    }
    int jx = 0;
    for (; jx + 4 <= n; jx += 4) {
      int s0 = __shfl(idx, jx, 64);
      int s1 = __shfl(idx, jx + 1, 64);
      int s2 = __shfl(idx, jx + 2, 64);
      int s3 = __shfl(idx, jx + 3, 64);
      float d0 = __shfl(dsv, jx, 64);
      float d1 = __shfl(dsv, jx + 1, 64);
      float d2 = __shfl(dsv, jx + 2, 64);
      float d3 = __shfl(dsv, jx + 3, 64);
      unsigned int v0 = g1[(size_t)s0 * 64 + lane];
      unsigned int v1 = g1[(size_t)s1 * 64 + lane];
      unsigned int v2 = g1[(size_t)s2 * 64 + lane];
      unsigned int v3 = g1[(size_t)s3 * 64 + lane];
      ax = fmaf(d0, bf_lo(v0), ax);
      ay = fmaf(d0, bf_hi(v0), ay);
      ax = fmaf(d1, bf_lo(v1), ax);
      ay = fmaf(d1, bf_hi(v1), ay);
      ax = fmaf(d2, bf_lo(v2), ax);
      ay = fmaf(d2, bf_hi(v2), ay);
      ax = fmaf(d3, bf_lo(v3), ax);
      ay = fmaf(d3, bf_hi(v3), ay);
    }
    for (; jx < n; ++jx) {
      int s0 = __shfl(idx, jx, 64);
      float d0 = __shfl(dsv, jx, 64);
      unsigned int v = g1[(size_t)s0 * 64 + lane];
      ax = fmaf(d0, bf_lo(v), ax);
      ay = fmaf(d0, bf_hi(v), ay);
    }
  }
  float2 b = ((const float2*)bias)[lane];
  float rx = fmaxf(fmaf(di, ax, b.x), 0.f);
  float ry = fmaxf(fmaf(di, ay, b.y), 0.f);
  ushort2 o;
  o.x = f2bf(rx);
  o.y = f2bf(ry);
  ((ushort2*)outh)[(size_t)wid * 64 + lane] = o;
}

// ---------------- launch ----------------

extern "C" void kernel_launch(void* const* d_in, const int* in_sizes, int n_in,
                              void* d_out, int out_size, void* d_ws, size_t ws_size,
                              hipStream_t stream) {
  const float* x = (const float*)d_in[0];
  const int* ei = (const int*)d_in[1];
  const float* W1 = (const float*)d_in[2];
  const float* b1 = (const float*)d_in[3];
  const float* W2 = (const float*)d_in[4];
  const float* b2 = (const float*)d_in[5];
  const float* W3 = (const float*)d_in[6];
  const float* b3 = (const float*)d_in[7];
  const float* Wo1 = (const float*)d_in[8];
  const float* bo1 = (const float*)d_in[9];
  const float* Wo2 = (const float*)d_in[10];
  const float* bo2 = (const float*)d_in[11];
  float* out = (float*)d_out;

  int M = in_sizes[0] / DHID;  // 50000
  int E = in_sizes[1] / 2;     // 800000

  int NPB = (M + NBUK - 1) / NBUK;  // nodes per bucket (196)
  int EPB = (E + NBLK - 1) / NBLK;  // edges per sort block
  int SCN = NBUK * NBLK;            // 50176

  // workspace layout (~54.1 MB peak). Weights at 4MiB+64KB — csr spans
  // [5MiB, 5MiB+3.2MB) and must NOT touch them (round-7 NaN bug).
  char* ws = (char*)d_ws;
  float* dis = (float*)(ws + 0);                        // M floats (200KB)
  int* rp = (int*)(ws + (1ull << 20));                  // M+1 ints
  int* Hist = (int*)(ws + (2ull << 20));                // SCN ints (200KB)
  int* S = (int*)(ws + (3ull << 20));                   // SCN ints
  int* blk = (int*)(ws + (4ull << 20));                 // <=256 ints (1KB)
  unsigned short* W1t = (unsigned short*)(ws + (4ull << 20) + 65536 + 0 * 32768);
  unsigned short* W2t = (unsigned short*)(ws + (4ull << 20) + 65536 + 1 * 32768);
  unsigned short* W3t = (unsigned short*)(ws + (4ull << 20) + 65536 + 2 * 32768);
  unsigned short* Wo1t = (unsigned short*)(ws + (4ull << 20) + 65536 + 3 * 32768);
  unsigned short* Wo2t = (unsigned short*)(ws + (4ull << 20) + 65536 + 4 * 32768);
  // weights end at 4MiB+64KB+160KB = 4,423,680 < 5MiB ✓
  int* csr = (int*)(ws + (5ull << 20));                 // E ints: [5MiB, 8.45MiB)
  unsigned short* gA = (unsigned short*)(ws + (9ull << 20));   // M*128 bf16
  unsigned short* gB = (unsigned short*)(ws + (22ull << 20));  // M*128 bf16
  unsigned short* hb = (unsigned short*)(ws + (35ull << 20));  // M*128 bf16
  int2* sorted = (int2*)(ws + (48ull << 20));           // E int2 (6.4 MB)

  int gG = (M + 63) / 64;  // 782
  int gA4 = (M + 3) / 4;   // agg: 4 waves/block, wave per node

  // weight prep (bf16 transpose), then layer-1 GEMM fused with sort pass 1
  k_prep<<<40, 256, 0, stream>>>(W1, W2, W3, Wo1, Wo2, W1t, W2t, W3t, Wo1t, Wo2t);
  k_gemm1_hist<<<gG + NBLK, 256, 0, stream>>>(x, W1t, gA, M, gG, ei, E, EPB, NPB, Hist);
  // scan Hist
  k_scan1<<<NBLK, 256, 0, stream>>>(Hist, S, blk, SCN);
  k_scan2<<<1, 256, 0, stream>>>(blk, NBLK);
  // sort pass 2 + 3
  k_scatter<<<NBLK, 256, 0, stream>>>(ei, E, EPB, NPB, S, blk, sorted);
  k_finalize<<<NBUK, 256, 0, stream>>>(sorted, S, blk, E, M, NPB, rp, dis, csr);

  // GCN layers (agg -> MFMA gemm)
  k_agg<<<gA4, 256, 0, stream>>>(gA, csr, rp, dis, b1, hb, M);
  k_mgemm<128, 0, 0><<<gG, 256, 0, stream>>>(hb, W2t, nullptr, gB, M);
  k_agg<<<gA4, 256, 0, stream>>>(gB, csr, rp, dis, b2, hb, M);
  k_mgemm<128, 0, 0><<<gG, 256, 0, stream>>>(hb, W3t, nullptr, gA, M);
  k_agg<<<gA4, 256, 0, stream>>>(gA, csr, rp, dis, b3, hb, M);
  // MLP head: t = hb@Wo1+bo1 (bf16, reuse gB), out = t@Wo2+bo2 (fp32)
  k_mgemm<128, 0, 1><<<gG, 256, 0, stream>>>(hb, Wo1t, bo1, gB, M);
  k_mgemm<64, 0, 2><<<gG, 256, 0, stream>>>(gB, Wo2t, bo2, out, M);
}